// Round 2
// baseline (1154.960 us; speedup 1.0000x reference)
//
#include <hip/hip_runtime.h>
#include <hip/hip_bf16.h>

#define B_    32
#define C_    128
#define H_    56
#define W_    56
#define OUT_  256
#define K_    4
#define HID_  64
#define HW_   (H_*W_)        // 3136
#define KV_   (C_*9)         // 1152
#define BANKS_ (OUT_*KV_)    // 294912 elems per k in weight_bank

#define OT_   8              // output channels per block
#define NI_   (54*54)        // interior pixel count = 2916

// ---------------------------------------------------------------------------
// Kernel 1: global average pool   pooled[b*C + c] = mean(x[b,c,:,:])
// ---------------------------------------------------------------------------
__global__ __launch_bounds__(256) void dc_pool(const float* __restrict__ x,
                                               float* __restrict__ pooled) {
    int bc = blockIdx.x;                       // b*C_ + c
    const float* p = x + (size_t)bc * HW_;
    float s = 0.f;
    for (int i = threadIdx.x; i < HW_; i += 256)
        s += p[i];
    // wave64 reduce
    for (int off = 32; off > 0; off >>= 1)
        s += __shfl_down(s, off, 64);
    __shared__ float red[4];
    int lane = threadIdx.x & 63, wv = threadIdx.x >> 6;
    if (lane == 0) red[wv] = s;
    __syncthreads();
    if (threadIdx.x == 0)
        pooled[bc] = (red[0] + red[1] + red[2] + red[3]) * (1.0f / HW_);
}

// ---------------------------------------------------------------------------
// Kernel 2: attn[b,k] = softmax(relu(pooled@fc1^T + b1)@fc2^T + b2)
// one block per batch sample, 64 threads
// ---------------------------------------------------------------------------
__global__ __launch_bounds__(64) void dc_attn(const float* __restrict__ pooled,
                                              const float* __restrict__ fc1w,
                                              const float* __restrict__ fc1b,
                                              const float* __restrict__ fc2w,
                                              const float* __restrict__ fc2b,
                                              float* __restrict__ attn) {
    int b = blockIdx.x, h = threadIdx.x;       // h in [0,64)
    __shared__ float pl[C_];
    __shared__ float hdn[HID_];
    __shared__ float logit[K_];
    pl[h]      = pooled[b*C_ + h];
    pl[h + 64] = pooled[b*C_ + 64 + h];
    __syncthreads();
    float s = fc1b[h];
    #pragma unroll 8
    for (int c = 0; c < C_; ++c)
        s += pl[c] * fc1w[h*C_ + c];
    hdn[h] = fmaxf(s, 0.f);
    __syncthreads();
    if (h < K_) {
        float t = fc2b[h];
        #pragma unroll 8
        for (int j = 0; j < HID_; ++j)
            t += hdn[j] * fc2w[h*HID_ + j];
        logit[h] = t;
    }
    __syncthreads();
    if (h == 0) {
        float m = fmaxf(fmaxf(logit[0], logit[1]), fmaxf(logit[2], logit[3]));
        float e0 = __expf(logit[0]-m), e1 = __expf(logit[1]-m);
        float e2 = __expf(logit[2]-m), e3 = __expf(logit[3]-m);
        float inv = 1.0f / (e0+e1+e2+e3);
        attn[b*K_+0] = e0*inv; attn[b*K_+1] = e1*inv;
        attn[b*K_+2] = e2*inv; attn[b*K_+3] = e3*inv;
    }
}

// ---------------------------------------------------------------------------
// Kernel 3: fused weight-synthesis + grouped conv.
// block = (b, og): 8 output channels, all 3136 pixels.
// Weights synthesized into LDS from bank+attn (once per block).
// Interior pixels (54x54): fixed 9-tap offsets, 4 pixels/thread.
// Border pixels (220): masked P=1 tail.
// ---------------------------------------------------------------------------
__global__ __launch_bounds__(256) void dc_conv(const float* __restrict__ x,
                                               const float* __restrict__ bank,
                                               const float* __restrict__ attn,
                                               float* __restrict__ out) {
    const int blk = blockIdx.x;
    const int b  = blk >> 5;          // 32 og-groups per batch
    const int og = blk & 31;          // OUT_/OT_ = 32

    __shared__ float w_s[OT_ * KV_];  // 8*1152*4 = 36864 B

    const float a0 = attn[b*K_ + 0];
    const float a1 = attn[b*K_ + 1];
    const float a2 = attn[b*K_ + 2];
    const float a3 = attn[b*K_ + 3];

    // synthesize this block's weights into LDS
    for (int idx = threadIdx.x; idx < OT_*KV_; idx += 256) {
        int o = idx / KV_;
        int r = idx - o * KV_;
        size_t gb = (size_t)(og*OT_ + o) * KV_ + r;
        float v = a0 * bank[gb]
                + a1 * bank[gb +   (size_t)BANKS_]
                + a2 * bank[gb + 2*(size_t)BANKS_]
                + a3 * bank[gb + 3*(size_t)BANKS_];
        w_s[idx] = v;
    }
    __syncthreads();

    const float* xplane0 = x + (size_t)b * C_ * HW_;
    const size_t obase = ((size_t)b * OUT_ + (size_t)og * OT_) * HW_;

    const int DOFF[9] = {-57,-56,-55,-1,0,1,55,56,57};

    // ---- interior: 3 passes of 4 pixels/thread (covers 2916 pixels) ----
    for (int pass = 0; pass < 3; ++pass) {
        int idx0 = pass * 1024 + threadIdx.x;
        int p[4]; bool st[4];
        #pragma unroll
        for (int i = 0; i < 4; ++i) {
            int id = idx0 + i * 256;
            st[i] = (id < NI_);
            if (id >= NI_) id = NI_ - 1;      // clamp: redundant compute, store masked
            int yy = id / 54;
            int xx = id - yy * 54;
            p[i] = (yy + 1) * 56 + (xx + 1);
        }
        float acc[OT_][4];
        #pragma unroll
        for (int o = 0; o < OT_; ++o)
            #pragma unroll
            for (int i = 0; i < 4; ++i) acc[o][i] = 0.f;

        const float* xb = xplane0;
        #pragma unroll 1
        for (int c = 0; c < C_; ++c, xb += HW_) {
            float xv[4][9];
            #pragma unroll
            for (int i = 0; i < 4; ++i)
                #pragma unroll
                for (int ij = 0; ij < 9; ++ij)
                    xv[i][ij] = xb[p[i] + DOFF[ij]];
            #pragma unroll
            for (int o = 0; o < OT_; ++o) {
                const float* wr = &w_s[o*KV_ + c*9];
                #pragma unroll
                for (int ij = 0; ij < 9; ++ij) {
                    float wv = wr[ij];
                    #pragma unroll
                    for (int i = 0; i < 4; ++i)
                        acc[o][i] += wv * xv[i][ij];
                }
            }
        }
        #pragma unroll
        for (int o = 0; o < OT_; ++o)
            #pragma unroll
            for (int i = 0; i < 4; ++i)
                if (st[i])
                    out[obase + (size_t)o * HW_ + p[i]] = acc[o][i];
    }

    // ---- border: 220 edge pixels, one per thread, masked taps ----
    {
        int t = threadIdx.x;
        if (t < 220) {
            int yy, xx;
            if      (t < 56)  { yy = 0;       xx = t;       }
            else if (t < 112) { yy = 55;      xx = t - 56;  }
            else if (t < 166) { yy = t - 111; xx = 0;       }
            else              { yy = t - 165; xx = 55;      }
            int p0 = yy * 56 + xx;
            int off[9]; float msk[9];
            #pragma unroll
            for (int dy = 0; dy < 3; ++dy) {
                int y2 = yy + dy - 1;
                bool vy = (unsigned)y2 < (unsigned)H_;
                #pragma unroll
                for (int dx = 0; dx < 3; ++dx) {
                    int x2 = xx + dx - 1;
                    bool v = vy && ((unsigned)x2 < (unsigned)W_);
                    off[dy*3+dx] = v ? (y2 * 56 + x2) : 0;
                    msk[dy*3+dx] = v ? 1.f : 0.f;
                }
            }
            float acc[OT_];
            #pragma unroll
            for (int o = 0; o < OT_; ++o) acc[o] = 0.f;
            const float* xb = xplane0;
            #pragma unroll 1
            for (int c = 0; c < C_; ++c, xb += HW_) {
                float xv[9];
                #pragma unroll
                for (int ij = 0; ij < 9; ++ij)
                    xv[ij] = msk[ij] * xb[off[ij]];
                #pragma unroll
                for (int o = 0; o < OT_; ++o) {
                    const float* wr = &w_s[o*KV_ + c*9];
                    #pragma unroll
                    for (int ij = 0; ij < 9; ++ij)
                        acc[o] += wr[ij] * xv[ij];
                }
            }
            #pragma unroll
            for (int o = 0; o < OT_; ++o)
                out[obase + (size_t)o * HW_ + p0] = acc[o];
        }
    }
}

// ---------------------------------------------------------------------------
extern "C" void kernel_launch(void* const* d_in, const int* in_sizes, int n_in,
                              void* d_out, int out_size, void* d_ws, size_t ws_size,
                              hipStream_t stream) {
    const float* x    = (const float*)d_in[0];
    const float* bank = (const float*)d_in[1];
    const float* fc1w = (const float*)d_in[2];
    const float* fc1b = (const float*)d_in[3];
    const float* fc2w = (const float*)d_in[4];
    const float* fc2b = (const float*)d_in[5];
    float* out = (float*)d_out;

    float* pooled = (float*)d_ws;              // B_*C_ floats
    float* attn   = pooled + B_*C_;            // B_*K_ floats

    dc_pool<<<B_*C_, 256, 0, stream>>>(x, pooled);
    dc_attn<<<B_, 64, 0, stream>>>(pooled, fc1w, fc1b, fc2w, fc2b, attn);
    dc_conv<<<B_ * (OUT_/OT_), 256, 0, stream>>>(x, bank, attn, out);
}

// Round 3
// 723.467 us; speedup vs baseline: 1.5964x; 1.5964x over previous
//
#include <hip/hip_runtime.h>
#include <hip/hip_bf16.h>

#define B_    32
#define C_    128
#define H_    56
#define W_    56
#define OUT_  256
#define K_    4
#define HID_  64
#define HW_   (H_*W_)        // 3136
#define KV_   (C_*9)         // 1152
#define TOTROW_ (B_*HW_)     // 100352 rows in xT

typedef __attribute__((ext_vector_type(8))) short short8_t;   // 8 x bf16
typedef __attribute__((ext_vector_type(4))) float float4_t;

typedef __hip_bfloat16 bf16;

__device__ __forceinline__ short f2bf(float v) {
    union { bf16 h; short s; } u; u.h = __float2bfloat16(v); return u.s;
}

// ---------------------------------------------------------------------------
// Kernel 1: global average pool
// ---------------------------------------------------------------------------
__global__ __launch_bounds__(256) void dc_pool(const float* __restrict__ x,
                                               float* __restrict__ pooled) {
    int bc = blockIdx.x;
    const float* p = x + (size_t)bc * HW_;
    float s = 0.f;
    for (int i = threadIdx.x; i < HW_; i += 256) s += p[i];
    for (int off = 32; off > 0; off >>= 1) s += __shfl_down(s, off, 64);
    __shared__ float red[4];
    int lane = threadIdx.x & 63, wv = threadIdx.x >> 6;
    if (lane == 0) red[wv] = s;
    __syncthreads();
    if (threadIdx.x == 0)
        pooled[bc] = (red[0]+red[1]+red[2]+red[3]) * (1.0f / HW_);
}

// ---------------------------------------------------------------------------
// Kernel 2: attn = softmax(relu(pooled@fc1^T)@fc2^T)
// ---------------------------------------------------------------------------
__global__ __launch_bounds__(64) void dc_attn(const float* __restrict__ pooled,
                                              const float* __restrict__ fc1w,
                                              const float* __restrict__ fc1b,
                                              const float* __restrict__ fc2w,
                                              const float* __restrict__ fc2b,
                                              float* __restrict__ attn) {
    int b = blockIdx.x, h = threadIdx.x;
    __shared__ float pl[C_];
    __shared__ float hdn[HID_];
    __shared__ float logit[K_];
    pl[h]      = pooled[b*C_ + h];
    pl[h + 64] = pooled[b*C_ + 64 + h];
    __syncthreads();
    float s = fc1b[h];
    #pragma unroll 8
    for (int c = 0; c < C_; ++c) s += pl[c] * fc1w[h*C_ + c];
    hdn[h] = fmaxf(s, 0.f);
    __syncthreads();
    if (h < K_) {
        float t = fc2b[h];
        #pragma unroll 8
        for (int j = 0; j < HID_; ++j) t += hdn[j] * fc2w[h*HID_ + j];
        logit[h] = t;
    }
    __syncthreads();
    if (h == 0) {
        float m = fmaxf(fmaxf(logit[0], logit[1]), fmaxf(logit[2], logit[3]));
        float e0 = __expf(logit[0]-m), e1 = __expf(logit[1]-m);
        float e2 = __expf(logit[2]-m), e3 = __expf(logit[3]-m);
        float inv = 1.0f / (e0+e1+e2+e3);
        attn[b*K_+0]=e0*inv; attn[b*K_+1]=e1*inv;
        attn[b*K_+2]=e2*inv; attn[b*K_+3]=e3*inv;
    }
}

// ---------------------------------------------------------------------------
// Kernel 3: weight synthesis  Ws[b][o][k=tap*128+c] (bf16)
//   = sum_kk attn[b][kk] * bank[kk][o][c*9+tap]
// One block per o; bank row staged in LDS once, reused for all 32 b.
// ---------------------------------------------------------------------------
__global__ __launch_bounds__(256) void dc_wsynth(const float* __restrict__ bank,
                                                 const float* __restrict__ attn,
                                                 bf16* __restrict__ Ws) {
    int o = blockIdx.x;
    __shared__ float wb[4*KV_];
    for (int i = threadIdx.x; i < 4*KV_; i += 256) {
        int kk = i / KV_, r = i - kk*KV_;
        wb[i] = bank[((size_t)kk*OUT_ + o)*KV_ + r];
    }
    __syncthreads();
    for (int b = 0; b < B_; ++b) {
        float a0 = attn[b*K_+0], a1 = attn[b*K_+1];
        float a2 = attn[b*K_+2], a3 = attn[b*K_+3];
        for (int i = threadIdx.x; i < KV_; i += 256) {
            int tap = i >> 7, c = i & 127;
            int r = c*9 + tap;
            float v = a0*wb[r] + a1*wb[KV_+r] + a2*wb[2*KV_+r] + a3*wb[3*KV_+r];
            Ws[((size_t)b*OUT_ + o)*KV_ + i] = __float2bfloat16(v);
        }
    }
}

// ---------------------------------------------------------------------------
// Kernel 4: transpose x -> xT[b][n][c] bf16 (channel-contiguous)
// ---------------------------------------------------------------------------
__global__ __launch_bounds__(256) void dc_xt(const float* __restrict__ x,
                                             short* __restrict__ xT) {
    int b = blockIdx.y, n0 = blockIdx.x * 128;
    __shared__ short t[C_][130];       // [c][n], pad to stay conflict-free
    for (int i = threadIdx.x; i < C_*128; i += 256) {
        int c = i >> 7, nn = i & 127;
        int n = n0 + nn;
        float v = (n < HW_) ? x[((size_t)b*C_ + c)*HW_ + n] : 0.f;
        t[c][nn] = f2bf(v);
    }
    __syncthreads();
    for (int i = threadIdx.x; i < C_*128; i += 256) {
        int n = i >> 7, c = i & 127;
        if (n0 + n < HW_)
            xT[((size_t)b*HW_ + n0 + n)*C_ + c] = t[c][n];
    }
}

// ---------------------------------------------------------------------------
// Kernel 5: zero-LDS implicit GEMM on MFMA.
//   C[b][m][n] = sum_k Ws[b][m][k] * xT[b][n + doff(tap)][c]   (k = tap*128+c)
// Block: 128m x 128n tile, 4 waves in 2x2; wave = 64x64 = 4x4 MFMA tiles.
// Fragments loaded directly from global (L2-resident); no LDS, no barriers.
// Border pixels get garbage (shifted reads) -> fixed by dc_border.
// ---------------------------------------------------------------------------
__global__ __launch_bounds__(256) void dc_gemm(const short* __restrict__ Ws,
                                               const short* __restrict__ xT,
                                               float* __restrict__ out) {
    const int b  = blockIdx.z;
    const int m0 = blockIdx.y * 128;
    const int n0 = blockIdx.x * 128;
    const int tid  = threadIdx.x;
    const int lane = tid & 63;
    const int wv   = tid >> 6;
    const int wm   = wv & 1, wn = wv >> 1;
    const int l16  = lane & 15, quad = lane >> 4;

    const short* Wb = Ws + (size_t)b * OUT_ * KV_;

    // A row pointers (k-contiguous); advance by 32 elems per k-step
    const short* ap[4];
    #pragma unroll
    for (int mi = 0; mi < 4; ++mi) {
        int am = m0 + wm*64 + mi*16 + l16;
        ap[mi] = Wb + (size_t)am * KV_ + quad*8;
    }
    int nidx[4];
    #pragma unroll
    for (int ni = 0; ni < 4; ++ni)
        nidx[ni] = n0 + wn*64 + ni*16 + l16;   // pixel index (may exceed HW_ on last tile)

    float4_t acc[4][4];
    #pragma unroll
    for (int mi = 0; mi < 4; ++mi)
        #pragma unroll
        for (int ni = 0; ni < 4; ++ni)
            acc[mi][ni] = (float4_t){0.f, 0.f, 0.f, 0.f};

    const int DOFF[9] = {-57,-56,-55,-1,0,1,55,56,57};

    for (int tap = 0; tap < 9; ++tap) {
        // B row pointers for this tap (clamped to the xT allocation)
        const short* bp[4];
        #pragma unroll
        for (int ni = 0; ni < 4; ++ni) {
            int r = b * HW_ + nidx[ni] + DOFF[tap];
            r = min(max(r, 0), TOTROW_ - 1);
            bp[ni] = xT + (size_t)r * C_ + quad*8;
        }
        const int kbase = tap * 128;
        #pragma unroll
        for (int cc = 0; cc < 128; cc += 32) {
            short8_t af[4], bfv[4];
            #pragma unroll
            for (int mi = 0; mi < 4; ++mi)
                af[mi] = *(const short8_t*)(ap[mi] + kbase + cc);
            #pragma unroll
            for (int ni = 0; ni < 4; ++ni)
                bfv[ni] = *(const short8_t*)(bp[ni] + cc);
            #pragma unroll
            for (int mi = 0; mi < 4; ++mi)
                #pragma unroll
                for (int ni = 0; ni < 4; ++ni)
                    acc[mi][ni] = __builtin_amdgcn_mfma_f32_16x16x32_bf16(
                        af[mi], bfv[ni], acc[mi][ni], 0, 0, 0);
        }
    }

    // Epilogue: D[m = quad*4 + reg][n = l16] per 16x16 tile
    const size_t obase = (size_t)b * OUT_ * HW_;
    #pragma unroll
    for (int mi = 0; mi < 4; ++mi) {
        int m = m0 + wm*64 + mi*16 + quad*4;
        #pragma unroll
        for (int ni = 0; ni < 4; ++ni) {
            int n = nidx[ni];
            if (n < HW_) {
                float* op = out + obase + (size_t)m * HW_ + n;
                #pragma unroll
                for (int r = 0; r < 4; ++r)
                    op[(size_t)r * HW_] = acc[mi][ni][r];
            }
        }
    }
}

// ---------------------------------------------------------------------------
// Kernel 6: border fix — recompute the 220 edge pixels per plane exactly
// (masked taps), overwriting dc_gemm's garbage there.
// Block = (b, og of 8 output channels); weights from Ws staged in LDS.
// ---------------------------------------------------------------------------
__global__ __launch_bounds__(256) void dc_border(const float* __restrict__ x,
                                                 const bf16* __restrict__ Ws,
                                                 float* __restrict__ out) {
    const int blk = blockIdx.x;
    const int b  = blk >> 5;
    const int og = blk & 31;

    __shared__ float w_s[8 * KV_];     // [o][k = tap*128 + c]
    for (int i = threadIdx.x; i < 8*KV_; i += 256)
        w_s[i] = __bfloat162float(Ws[((size_t)b*OUT_ + og*8)*KV_ + i]);
    __syncthreads();

    const float* xb0 = x + (size_t)b * C_ * HW_;
    const size_t obase = ((size_t)b * OUT_ + (size_t)og * 8) * HW_;

    int t = threadIdx.x;
    if (t >= 220) return;
    int yy, xx;
    if      (t < 56)  { yy = 0;       xx = t;       }
    else if (t < 112) { yy = 55;      xx = t - 56;  }
    else if (t < 166) { yy = t - 111; xx = 0;       }
    else              { yy = t - 165; xx = 55;      }
    int p0 = yy * W_ + xx;
    int off[9]; float msk[9];
    #pragma unroll
    for (int dy = 0; dy < 3; ++dy) {
        int y2 = yy + dy - 1;
        bool vy = (unsigned)y2 < (unsigned)H_;
        #pragma unroll
        for (int dx = 0; dx < 3; ++dx) {
            int x2 = xx + dx - 1;
            bool v = vy && ((unsigned)x2 < (unsigned)W_);
            off[dy*3+dx] = v ? (y2 * W_ + x2) : 0;
            msk[dy*3+dx] = v ? 1.f : 0.f;
        }
    }
    float acc[8];
    #pragma unroll
    for (int o = 0; o < 8; ++o) acc[o] = 0.f;
    const float* xb = xb0;
    #pragma unroll 1
    for (int c = 0; c < C_; ++c, xb += HW_) {
        float xv[9];
        #pragma unroll
        for (int ij = 0; ij < 9; ++ij)
            xv[ij] = msk[ij] * xb[off[ij]];
        #pragma unroll
        for (int o = 0; o < 8; ++o) {
            #pragma unroll
            for (int ij = 0; ij < 9; ++ij)
                acc[o] += w_s[o*KV_ + ij*128 + c] * xv[ij];
        }
    }
    #pragma unroll
    for (int o = 0; o < 8; ++o)
        out[obase + (size_t)o * HW_ + p0] = acc[o];
}

// ---------------------------------------------------------------------------
extern "C" void kernel_launch(void* const* d_in, const int* in_sizes, int n_in,
                              void* d_out, int out_size, void* d_ws, size_t ws_size,
                              hipStream_t stream) {
    const float* x    = (const float*)d_in[0];
    const float* bank = (const float*)d_in[1];
    const float* fc1w = (const float*)d_in[2];
    const float* fc1b = (const float*)d_in[3];
    const float* fc2w = (const float*)d_in[4];
    const float* fc2b = (const float*)d_in[5];
    float* out = (float*)d_out;

    char* ws = (char*)d_ws;
    float* pooled = (float*)ws;                          // 16 KB
    float* attn   = (float*)(ws + 16*1024);              // 512 B
    bf16*  Ws     = (bf16*) (ws + 32*1024);              // 32*256*1152*2 = 18,874,368 B
    short* xT     = (short*)(ws + 32*1024 + 18874368);   // 32*3136*128*2 = 25,690,112 B

    dc_pool  <<<B_*C_, 256, 0, stream>>>(x, pooled);
    dc_attn  <<<B_,     64, 0, stream>>>(pooled, fc1w, fc1b, fc2w, fc2b, attn);
    dc_wsynth<<<OUT_,  256, 0, stream>>>(bank, attn, Ws);
    dc_xt    <<<dim3(25, B_), 256, 0, stream>>>(x, xT);
    dc_gemm  <<<dim3(25, 2, B_), 256, 0, stream>>>((const short*)Ws, xT, out);
    dc_border<<<B_*32, 256, 0, stream>>>(x, Ws, out);
}

// Round 4
// 448.790 us; speedup vs baseline: 2.5735x; 1.6120x over previous
//
#include <hip/hip_runtime.h>
#include <hip/hip_bf16.h>

#define B_    32
#define C_    128
#define H_    56
#define W_    56
#define OUT_  256
#define K_    4
#define HID_  64
#define HW_   (H_*W_)        // 3136
#define KV_   (C_*9)         // 1152
#define PH_   58
#define PW_   58
#define PP_   (PH_*PW_)      // 3364 padded pixels per sample

typedef __attribute__((ext_vector_type(8))) short short8_t;   // 8 x bf16
typedef __attribute__((ext_vector_type(4))) float float4_t;

typedef __hip_bfloat16 bf16;

__device__ __forceinline__ short f2bf(float v) {
    union { bf16 h; short s; } u; u.h = __float2bfloat16(v); return u.s;
}

// ---------------------------------------------------------------------------
// Kernel 1: global average pool
// ---------------------------------------------------------------------------
__global__ __launch_bounds__(256) void dc_pool(const float* __restrict__ x,
                                               float* __restrict__ pooled) {
    int bc = blockIdx.x;
    const float* p = x + (size_t)bc * HW_;
    float s = 0.f;
    for (int i = threadIdx.x; i < HW_; i += 256) s += p[i];
    for (int off = 32; off > 0; off >>= 1) s += __shfl_down(s, off, 64);
    __shared__ float red[4];
    int lane = threadIdx.x & 63, wv = threadIdx.x >> 6;
    if (lane == 0) red[wv] = s;
    __syncthreads();
    if (threadIdx.x == 0)
        pooled[bc] = (red[0]+red[1]+red[2]+red[3]) * (1.0f / HW_);
}

// ---------------------------------------------------------------------------
// Kernel 2: attn = softmax(relu(pooled@fc1^T)@fc2^T)
// ---------------------------------------------------------------------------
__global__ __launch_bounds__(64) void dc_attn(const float* __restrict__ pooled,
                                              const float* __restrict__ fc1w,
                                              const float* __restrict__ fc1b,
                                              const float* __restrict__ fc2w,
                                              const float* __restrict__ fc2b,
                                              float* __restrict__ attn) {
    int b = blockIdx.x, h = threadIdx.x;
    __shared__ float pl[C_];
    __shared__ float hdn[HID_];
    __shared__ float logit[K_];
    pl[h]      = pooled[b*C_ + h];
    pl[h + 64] = pooled[b*C_ + 64 + h];
    __syncthreads();
    float s = fc1b[h];
    #pragma unroll 8
    for (int c = 0; c < C_; ++c) s += pl[c] * fc1w[h*C_ + c];
    hdn[h] = fmaxf(s, 0.f);
    __syncthreads();
    if (h < K_) {
        float t = fc2b[h];
        #pragma unroll 8
        for (int j = 0; j < HID_; ++j) t += hdn[j] * fc2w[h*HID_ + j];
        logit[h] = t;
    }
    __syncthreads();
    if (h == 0) {
        float m = fmaxf(fmaxf(logit[0], logit[1]), fmaxf(logit[2], logit[3]));
        float e0 = __expf(logit[0]-m), e1 = __expf(logit[1]-m);
        float e2 = __expf(logit[2]-m), e3 = __expf(logit[3]-m);
        float inv = 1.0f / (e0+e1+e2+e3);
        attn[b*K_+0]=e0*inv; attn[b*K_+1]=e1*inv;
        attn[b*K_+2]=e2*inv; attn[b*K_+3]=e3*inv;
    }
}

// ---------------------------------------------------------------------------
// Kernel 3: weight synthesis  Ws[b][o][k=tap*128+c] (bf16)
//   = sum_kk attn[b][kk] * bank[kk][o][c*9+tap]
// One block per o; bank row staged in LDS once, reused for all 32 b.
// ---------------------------------------------------------------------------
__global__ __launch_bounds__(256) void dc_wsynth(const float* __restrict__ bank,
                                                 const float* __restrict__ attn,
                                                 bf16* __restrict__ Ws) {
    int o = blockIdx.x;
    __shared__ float wb[4*KV_];
    for (int i = threadIdx.x; i < 4*KV_; i += 256) {
        int kk = i / KV_, r = i - kk*KV_;
        wb[i] = bank[((size_t)kk*OUT_ + o)*KV_ + r];
    }
    __syncthreads();
    for (int b = 0; b < B_; ++b) {
        float a0 = attn[b*K_+0], a1 = attn[b*K_+1];
        float a2 = attn[b*K_+2], a3 = attn[b*K_+3];
        unsigned* dst = (unsigned*)&Ws[((size_t)b*OUT_ + o)*KV_];
        for (int ii = threadIdx.x; ii < KV_/2; ii += 256) {
            int i0 = 2*ii;
            int tap0 = i0 >> 7, c0 = i0 & 127;
            int i1 = i0 + 1;
            int tap1 = i1 >> 7, c1 = i1 & 127;
            float v0 = a0*wb[c0*9+tap0] + a1*wb[KV_+c0*9+tap0]
                     + a2*wb[2*KV_+c0*9+tap0] + a3*wb[3*KV_+c0*9+tap0];
            float v1 = a0*wb[c1*9+tap1] + a1*wb[KV_+c1*9+tap1]
                     + a2*wb[2*KV_+c1*9+tap1] + a3*wb[3*KV_+c1*9+tap1];
            union { unsigned short u[2]; unsigned v; } pk;
            pk.u[0] = (unsigned short)f2bf(v0);
            pk.u[1] = (unsigned short)f2bf(v1);
            dst[ii] = pk.v;
        }
    }
}

// ---------------------------------------------------------------------------
// Kernel 4: transpose x -> zero-PADDED xTp[b][pp=58x58][c] bf16
// Pad ring rows are written as true zeros (ws is poisoned each launch).
// ---------------------------------------------------------------------------
__global__ __launch_bounds__(256) void dc_xt(const float* __restrict__ x,
                                             short* __restrict__ xTp) {
    int b = blockIdx.y, n0 = blockIdx.x * 128;   // 27 x-blocks cover 3456 >= 3364
    __shared__ short t[C_][130];
    for (int i = threadIdx.x; i < C_*128; i += 256) {
        int c = i >> 7, nn = i & 127;
        int pp = n0 + nn;
        int py = pp / PW_, px = pp - py*PW_;
        bool valid = (pp < PP_) & (py >= 1) & (py <= H_) & (px >= 1) & (px <= W_);
        float v = valid ? x[((size_t)b*C_ + c)*HW_ + (py-1)*W_ + (px-1)] : 0.f;
        t[c][nn] = f2bf(v);
    }
    __syncthreads();
    for (int i = threadIdx.x; i < 64*128; i += 256) {
        int nn = i >> 6, c2 = (i & 63) * 2;
        int pp = n0 + nn;
        if (pp < PP_) {
            union { unsigned short u[2]; unsigned v; } pk;
            pk.u[0] = (unsigned short)t[c2][nn];
            pk.u[1] = (unsigned short)t[c2+1][nn];
            *(unsigned*)&xTp[((size_t)b*PP_ + pp)*C_ + c2] = pk.v;
        }
    }
}

// ---------------------------------------------------------------------------
// Kernel 5: zero-LDS implicit GEMM on MFMA (exact everywhere via padded xTp).
//   C[b][m][n] = sum_{tap,c} Ws[b][m][tap*128+c] * xTp[b][pad(n)+doffp(tap)][c]
// Block: 128m x 128n tile, 4 waves in 2x2; wave = 64x64 = 4x4 MFMA tiles.
// ---------------------------------------------------------------------------
__global__ __launch_bounds__(256) void dc_gemm(const short* __restrict__ Ws,
                                               const short* __restrict__ xTp,
                                               float* __restrict__ out) {
    const int b  = blockIdx.z;
    const int m0 = blockIdx.y * 128;
    const int n0 = blockIdx.x * 128;
    const int tid  = threadIdx.x;
    const int lane = tid & 63;
    const int wv   = tid >> 6;
    const int wm   = wv & 1, wn = wv >> 1;
    const int l16  = lane & 15, quad = lane >> 4;

    const short* Wb = Ws + (size_t)b * OUT_ * KV_;

    const short* ap[4];
    #pragma unroll
    for (int mi = 0; mi < 4; ++mi) {
        int am = m0 + wm*64 + mi*16 + l16;
        ap[mi] = Wb + (size_t)am * KV_ + quad*8;
    }

    int nidx[4];
    const short* bpbase[4];
    #pragma unroll
    for (int ni = 0; ni < 4; ++ni) {
        nidx[ni] = n0 + wn*64 + ni*16 + l16;          // output pixel (may be >= HW_)
        int idc = min(nidx[ni], HW_ - 1);
        int y = idc / W_, xx2 = idc - y * W_;
        int pbc = (y + 1) * PW_ + (xx2 + 1);          // padded center pixel
        bpbase[ni] = xTp + ((size_t)b * PP_ + pbc) * C_ + quad*8;
    }

    float4_t acc[4][4];
    #pragma unroll
    for (int mi = 0; mi < 4; ++mi)
        #pragma unroll
        for (int ni = 0; ni < 4; ++ni)
            acc[mi][ni] = (float4_t){0.f, 0.f, 0.f, 0.f};

    const int DOFFP[9] = {-59,-58,-57,-1,0,1,57,58,59};

    for (int tap = 0; tap < 9; ++tap) {
        const short* bp[4];
        #pragma unroll
        for (int ni = 0; ni < 4; ++ni)
            bp[ni] = bpbase[ni] + DOFFP[tap] * C_;
        const int kbase = tap * 128;
        #pragma unroll
        for (int cc = 0; cc < 128; cc += 32) {
            short8_t af[4], bfv[4];
            #pragma unroll
            for (int mi = 0; mi < 4; ++mi)
                af[mi] = *(const short8_t*)(ap[mi] + kbase + cc);
            #pragma unroll
            for (int ni = 0; ni < 4; ++ni)
                bfv[ni] = *(const short8_t*)(bp[ni] + cc);
            #pragma unroll
            for (int mi = 0; mi < 4; ++mi)
                #pragma unroll
                for (int ni = 0; ni < 4; ++ni)
                    acc[mi][ni] = __builtin_amdgcn_mfma_f32_16x16x32_bf16(
                        af[mi], bfv[ni], acc[mi][ni], 0, 0, 0);
        }
    }

    // Epilogue: D[m = quad*4 + reg][n = l16] per 16x16 tile
    const size_t obase = (size_t)b * OUT_ * HW_;
    #pragma unroll
    for (int mi = 0; mi < 4; ++mi) {
        int m = m0 + wm*64 + mi*16 + quad*4;
        #pragma unroll
        for (int ni = 0; ni < 4; ++ni) {
            int n = nidx[ni];
            if (n < HW_) {
                float* op = out + obase + (size_t)m * HW_ + n;
                #pragma unroll
                for (int r = 0; r < 4; ++r)
                    op[(size_t)r * HW_] = acc[mi][ni][r];
            }
        }
    }
}

// ---------------------------------------------------------------------------
extern "C" void kernel_launch(void* const* d_in, const int* in_sizes, int n_in,
                              void* d_out, int out_size, void* d_ws, size_t ws_size,
                              hipStream_t stream) {
    const float* x    = (const float*)d_in[0];
    const float* bank = (const float*)d_in[1];
    const float* fc1w = (const float*)d_in[2];
    const float* fc1b = (const float*)d_in[3];
    const float* fc2w = (const float*)d_in[4];
    const float* fc2b = (const float*)d_in[5];
    float* out = (float*)d_out;

    char* ws = (char*)d_ws;
    float* pooled = (float*)ws;                          // 16 KB
    float* attn   = (float*)(ws + 16*1024);              // 512 B
    bf16*  Ws     = (bf16*) (ws + 32*1024);              // 32*256*1152*2 = 18,874,368 B
    short* xTp    = (short*)(ws + 32*1024 + 18874368);   // 32*3364*128*2 = 27,557,888 B

    dc_pool  <<<B_*C_, 256, 0, stream>>>(x, pooled);
    dc_attn  <<<B_,     64, 0, stream>>>(pooled, fc1w, fc1b, fc2w, fc2b, attn);
    dc_wsynth<<<OUT_,  256, 0, stream>>>(bank, attn, Ws);
    dc_xt    <<<dim3(27, B_), 256, 0, stream>>>(x, xTp);
    dc_gemm  <<<dim3(25, 2, B_), 256, 0, stream>>>((const short*)Ws, xTp, out);
}

// Round 5
// 358.767 us; speedup vs baseline: 3.2193x; 1.2509x over previous
//
#include <hip/hip_runtime.h>
#include <hip/hip_bf16.h>

#define B_    32
#define C_    128
#define H_    56
#define W_    56
#define OUT_  256
#define K_    4
#define HID_  64
#define HW_   (H_*W_)        // 3136
#define KV_   (C_*9)         // 1152
#define PH_   58
#define PW_   58
#define PP_   (PH_*PW_)      // 3364 padded pixels per sample

typedef __attribute__((ext_vector_type(8))) short short8_t;   // 8 x bf16
typedef __attribute__((ext_vector_type(4))) float float4_t;

typedef __hip_bfloat16 bf16;

__device__ __forceinline__ short f2bf(float v) {
    union { bf16 h; short s; } u; u.h = __float2bfloat16(v); return u.s;
}

typedef __attribute__((address_space(1))) const unsigned int* gas_t;
typedef __attribute__((address_space(3))) unsigned int* las_t;

// async global->LDS, 16 B per lane; LDS dest = wave-uniform base + lane*16
__device__ __forceinline__ void gl_lds16(const short* g, short* l) {
    __builtin_amdgcn_global_load_lds((gas_t)(const void*)g, (las_t)(void*)l, 16, 0, 0);
}

// ---------------------------------------------------------------------------
// Kernel 1: fused  x -> zero-padded xTp[b][58*58][c] (bf16)  +  global avg pool
// (pooled must be zeroed before launch; accumulated with atomics)
// ---------------------------------------------------------------------------
__global__ __launch_bounds__(256) void dc_xt(const float* __restrict__ x,
                                             short* __restrict__ xTp,
                                             float* __restrict__ pooled) {
    int b = blockIdx.y, n0 = blockIdx.x * 128;   // 27 x-blocks cover 3456 >= 3364
    __shared__ short t[C_][130];
    int lane = threadIdx.x & 63;
    for (int i = threadIdx.x; i < C_*128; i += 256) {
        int c = i >> 7, nn = i & 127;            // c is wave-uniform per iteration
        int pp = n0 + nn;
        int py = pp / PW_, px = pp - py*PW_;
        bool valid = (pp < PP_) & (py >= 1) & (py <= H_) & (px >= 1) & (px <= W_);
        float v = valid ? x[((size_t)b*C_ + c)*HW_ + (py-1)*W_ + (px-1)] : 0.f;
        t[c][nn] = f2bf(v);
        // pool: wave-reduce v (c uniform across the wave here)
        float s = v;
        for (int off = 32; off > 0; off >>= 1) s += __shfl_down(s, off, 64);
        if (lane == 0 && s != 0.f) atomicAdd(&pooled[b*C_ + c], s);
    }
    __syncthreads();
    for (int i = threadIdx.x; i < 64*128; i += 256) {
        int nn = i >> 6, c2 = (i & 63) * 2;
        int pp = n0 + nn;
        if (pp < PP_) {
            union { unsigned short u[2]; unsigned v; } pk;
            pk.u[0] = (unsigned short)t[c2][nn];
            pk.u[1] = (unsigned short)t[c2+1][nn];
            *(unsigned*)&xTp[((size_t)b*PP_ + pp)*C_ + c2] = pk.v;
        }
    }
}

// ---------------------------------------------------------------------------
// Kernel 2: attn = softmax(relu((pooled/HW)@fc1^T)@fc2^T)
// ---------------------------------------------------------------------------
__global__ __launch_bounds__(64) void dc_attn(const float* __restrict__ pooled,
                                              const float* __restrict__ fc1w,
                                              const float* __restrict__ fc1b,
                                              const float* __restrict__ fc2w,
                                              const float* __restrict__ fc2b,
                                              float* __restrict__ attn) {
    int b = blockIdx.x, h = threadIdx.x;
    __shared__ float pl[C_];
    __shared__ float hdn[HID_];
    __shared__ float logit[K_];
    pl[h]      = pooled[b*C_ + h]      * (1.0f / HW_);
    pl[h + 64] = pooled[b*C_ + 64 + h] * (1.0f / HW_);
    __syncthreads();
    float s = fc1b[h];
    #pragma unroll 8
    for (int c = 0; c < C_; ++c) s += pl[c] * fc1w[h*C_ + c];
    hdn[h] = fmaxf(s, 0.f);
    __syncthreads();
    if (h < K_) {
        float t = fc2b[h];
        #pragma unroll 8
        for (int j = 0; j < HID_; ++j) t += hdn[j] * fc2w[h*HID_ + j];
        logit[h] = t;
    }
    __syncthreads();
    if (h == 0) {
        float m = fmaxf(fmaxf(logit[0], logit[1]), fmaxf(logit[2], logit[3]));
        float e0 = __expf(logit[0]-m), e1 = __expf(logit[1]-m);
        float e2 = __expf(logit[2]-m), e3 = __expf(logit[3]-m);
        float inv = 1.0f / (e0+e1+e2+e3);
        attn[b*K_+0]=e0*inv; attn[b*K_+1]=e1*inv;
        attn[b*K_+2]=e2*inv; attn[b*K_+3]=e3*inv;
    }
}

// ---------------------------------------------------------------------------
// Kernel 3: weight synthesis  Ws[b][o][k=tap*128+c] (bf16)
// grid (OUT_, 4): block = (o, group of 8 samples); bank row staged in LDS once.
// ---------------------------------------------------------------------------
__global__ __launch_bounds__(256) void dc_wsynth(const float* __restrict__ bank,
                                                 const float* __restrict__ attn,
                                                 bf16* __restrict__ Ws) {
    int o = blockIdx.x;
    int b0 = blockIdx.y * 8;
    __shared__ float wb[4*KV_];
    for (int i = threadIdx.x; i < 4*KV_; i += 256) {
        int kk = i / KV_, r = i - kk*KV_;
        wb[i] = bank[((size_t)kk*OUT_ + o)*KV_ + r];
    }
    __syncthreads();
    for (int bi = 0; bi < 8; ++bi) {
        int b = b0 + bi;
        float a0 = attn[b*K_+0], a1 = attn[b*K_+1];
        float a2 = attn[b*K_+2], a3 = attn[b*K_+3];
        unsigned* dst = (unsigned*)&Ws[((size_t)b*OUT_ + o)*KV_];
        for (int ii = threadIdx.x; ii < KV_/2; ii += 256) {
            int i0 = 2*ii;
            int tap0 = i0 >> 7, c0 = i0 & 127;
            int i1 = i0 + 1;
            int tap1 = i1 >> 7, c1 = i1 & 127;
            float v0 = a0*wb[c0*9+tap0] + a1*wb[KV_+c0*9+tap0]
                     + a2*wb[2*KV_+c0*9+tap0] + a3*wb[3*KV_+c0*9+tap0];
            float v1 = a0*wb[c1*9+tap1] + a1*wb[KV_+c1*9+tap1]
                     + a2*wb[2*KV_+c1*9+tap1] + a3*wb[3*KV_+c1*9+tap1];
            union { unsigned short u[2]; unsigned v; } pk;
            pk.u[0] = (unsigned short)f2bf(v0);
            pk.u[1] = (unsigned short)f2bf(v1);
            dst[ii] = pk.v;
        }
    }
}

// ---------------------------------------------------------------------------
// Kernel 4: LDS-staged implicit GEMM (m97 structure, BK=64).
//   C[b][m][n] = sum_{tap,c} Ws[b][m][tap*128+c] * xTp[b][pad(n)+doffp(tap)][c]
// Block 128m x 128n, 4 waves 2x2 (64x64 each). A/B tiles staged via
// global_load_lds(16B) into LDS in MFMA-fragment order:
//   segment t (0..15): rows r = (t>>1)*16 + l16, k-half kq = t&1,
//   LDS short-offset = t*512 + lane*8  (lane = quad*16 + l16).
// Fragment ds_read_b128 at lane*16B  -> conflict-free, exact lane match.
// ---------------------------------------------------------------------------
__global__ __launch_bounds__(256) void dc_gemm(const short* __restrict__ Ws,
                                               const short* __restrict__ xTp,
                                               float* __restrict__ out) {
    const int b  = blockIdx.z;
    const int m0 = blockIdx.y * 128;
    const int n0 = blockIdx.x * 128;
    const int tid  = threadIdx.x;
    const int lane = tid & 63;
    const int wv   = tid >> 6;
    const int wm   = wv & 1, wn = wv >> 1;
    const int l16  = lane & 15, quad = lane >> 4;

    __shared__ short lA[128*64];   // 16 KB
    __shared__ short lB[128*64];   // 16 KB

    // --- staging source pointers: wave wv stages segments t = 4*wv + j ---
    const short* aG[4];
    const short* bG[4];
    short* aL[4];
    short* bL[4];
    #pragma unroll
    for (int j = 0; j < 4; ++j) {
        int t = 4*wv + j;
        int row = (t >> 1) * 16 + l16;
        int kq  = t & 1;
        aG[j] = Ws + ((size_t)b*OUT_ + m0 + row)*KV_ + kq*32 + quad*8;
        int n = n0 + row;
        int idc = min(n, HW_ - 1);
        int y = idc / W_, xx2 = idc - y * W_;
        int pbc = (y + 1) * PW_ + (xx2 + 1);
        bG[j] = xTp + ((size_t)b*PP_ + pbc)*C_ + kq*32 + quad*8;
        aL[j] = lA + t*512;
        bL[j] = lB + t*512;
    }

    int nidx[4];
    #pragma unroll
    for (int ni = 0; ni < 4; ++ni)
        nidx[ni] = n0 + wn*64 + ni*16 + l16;

    float4_t acc[4][4];
    #pragma unroll
    for (int mi = 0; mi < 4; ++mi)
        #pragma unroll
        for (int ni = 0; ni < 4; ++ni)
            acc[mi][ni] = (float4_t){0.f, 0.f, 0.f, 0.f};

    for (int tap = 0; tap < 9; ++tap) {
        int ty = tap / 3, tx = tap - 3*ty;
        int doff = (ty - 1) * PW_ + (tx - 1);
        #pragma unroll
        for (int half = 0; half < 2; ++half) {
            const int kk = tap*128 + half*64;   // A column base
            const int cc = half*64;             // B column base
            #pragma unroll
            for (int j = 0; j < 4; ++j) {
                gl_lds16(aG[j] + kk, aL[j]);
                gl_lds16(bG[j] + doff*C_ + cc, bL[j]);
            }
            __syncthreads();                    // drains vmcnt(0), publishes LDS
            #pragma unroll
            for (int kq = 0; kq < 2; ++kq) {
                short8_t af[4], bf[4];
                #pragma unroll
                for (int mi = 0; mi < 4; ++mi)
                    af[mi] = *(const short8_t*)(lA + ((wm*4+mi)*2 + kq)*512 + lane*8);
                #pragma unroll
                for (int ni = 0; ni < 4; ++ni)
                    bf[ni] = *(const short8_t*)(lB + ((wn*4+ni)*2 + kq)*512 + lane*8);
                #pragma unroll
                for (int mi = 0; mi < 4; ++mi)
                    #pragma unroll
                    for (int ni = 0; ni < 4; ++ni)
                        acc[mi][ni] = __builtin_amdgcn_mfma_f32_16x16x32_bf16(
                            af[mi], bf[ni], acc[mi][ni], 0, 0, 0);
            }
            __syncthreads();                    // all reads done before next overwrite
        }
    }

    // Epilogue: D[m = quad*4 + reg][n = l16] per 16x16 tile
    const size_t obase = (size_t)b * OUT_ * HW_;
    #pragma unroll
    for (int mi = 0; mi < 4; ++mi) {
        int m = m0 + wm*64 + mi*16 + quad*4;
        #pragma unroll
        for (int ni = 0; ni < 4; ++ni) {
            int n = nidx[ni];
            if (n < HW_) {
                float* op = out + obase + (size_t)m * HW_ + n;
                #pragma unroll
                for (int r = 0; r < 4; ++r)
                    op[(size_t)r * HW_] = acc[mi][ni][r];
            }
        }
    }
}

// ---------------------------------------------------------------------------
extern "C" void kernel_launch(void* const* d_in, const int* in_sizes, int n_in,
                              void* d_out, int out_size, void* d_ws, size_t ws_size,
                              hipStream_t stream) {
    const float* x    = (const float*)d_in[0];
    const float* bank = (const float*)d_in[1];
    const float* fc1w = (const float*)d_in[2];
    const float* fc1b = (const float*)d_in[3];
    const float* fc2w = (const float*)d_in[4];
    const float* fc2b = (const float*)d_in[5];
    float* out = (float*)d_out;

    char* ws = (char*)d_ws;
    float* pooled = (float*)ws;                          // 16 KB (zeroed below)
    float* attn   = (float*)(ws + 16*1024);              // 512 B
    bf16*  Ws     = (bf16*) (ws + 32*1024);              // 18,874,368 B
    short* xTp    = (short*)(ws + 32*1024 + 18874368);   // 27,557,888 B

    hipMemsetAsync(pooled, 0, B_*C_*sizeof(float), stream);
    dc_xt    <<<dim3(27, B_), 256, 0, stream>>>(x, xTp, pooled);
    dc_attn  <<<B_,     64, 0, stream>>>(pooled, fc1w, fc1b, fc2w, fc2b, attn);
    dc_wsynth<<<dim3(OUT_, 4), 256, 0, stream>>>(bank, attn, Ws);
    dc_gemm  <<<dim3(25, 2, B_), 256, 0, stream>>>((const short*)Ws, xTp, out);
}